// Round 3
// baseline (1571.873 us; speedup 1.0000x reference)
//
#include <hip/hip_runtime.h>
#include <hip/hip_bf16.h>

#define AF 128
#define BF 128
#define BROWS 128            // rows per bucket
#define PASSA_CHUNK 8192

typedef __attribute__((ext_vector_type(8))) short bf16x8;
typedef __attribute__((ext_vector_type(4))) float f32x4;

__device__ inline unsigned short f2bf(float f) {
    unsigned int u = __float_as_uint(f);
    u += 0x7FFF + ((u >> 16) & 1);          // round-to-nearest-even
    return (unsigned short)(u >> 16);
}
__device__ inline unsigned int pk2bf(float x, float y) {
    __hip_bfloat162 h = __float22bfloat162_rn(make_float2(x, y));
    return *(unsigned int*)&h;
}
__device__ inline float bflo(unsigned int u) { return __uint_as_float(u << 16); }
__device__ inline float bfhi(unsigned int u) { return __uint_as_float(u & 0xFFFF0000u); }

// ---- one-time: Wt[n][k] = bf16(W[k][n]), 128x128 ----
__global__ void wtrans_kernel(const float* __restrict__ W, unsigned short* __restrict__ Wt) {
    int idx = blockIdx.x * 256 + threadIdx.x;   // grid 64 x 256 = 16384
    int n = idx & 127, k = idx >> 7;
    Wt[n * 128 + k] = f2bf(W[(size_t)k * 128 + n]);
}

// ---- MFMA GEMM: Sup[NB][128] bf16 = Bin @ W, stored interleaved:
//      Sup[row*128 + 2*(f&63) + (f>>6)]  so one uint at lane*2 holds feats (lane, lane+64)
__global__ __launch_bounds__(256) void gemm_mfma_kernel(const float* __restrict__ Bin,
                                                        const unsigned short* __restrict__ Wt,
                                                        unsigned short* __restrict__ Sup, int NB) {
    __shared__ unsigned short As[64][136];
    __shared__ unsigned short Ws[128][136];
    const int tid = threadIdx.x;
    const int lane = tid & 63;
    const int wave = tid >> 6;
    const int row0 = blockIdx.x * 64;

    // stage A tile (fp32 -> bf16 packed): 4 threads per row, 32 floats each
    {
        int lr = tid >> 2;
        int ks = (tid & 3) * 32;
        int gr = row0 + lr;
        const float4* src = (const float4*)(Bin + (size_t)gr * BF + ks);
        #pragma unroll
        for (int i = 0; i < 4; i++) {
            float4 a = (gr < NB) ? src[2 * i]     : make_float4(0.f, 0.f, 0.f, 0.f);
            float4 b = (gr < NB) ? src[2 * i + 1] : make_float4(0.f, 0.f, 0.f, 0.f);
            uint4 u;
            u.x = pk2bf(a.x, a.y); u.y = pk2bf(a.z, a.w);
            u.z = pk2bf(b.x, b.y); u.w = pk2bf(b.z, b.w);
            *(uint4*)(&As[lr][ks + i * 8]) = u;
        }
    }
    // stage Wt (already bf16): thread copies 128 B
    {
        int r = tid >> 1;
        int c = (tid & 1) * 64;
        const uint4* src = (const uint4*)(Wt + r * 128 + c);
        uint4* dst = (uint4*)(&Ws[r][c]);
        #pragma unroll
        for (int i = 0; i < 8; i++) dst[i] = src[i];
    }
    __syncthreads();

    const int m = lane & 15;
    const int quad = lane >> 4;

    bf16x8 af[4];
    #pragma unroll
    for (int ks = 0; ks < 4; ks++)
        af[ks] = *(const bf16x8*)(&As[wave * 16 + m][ks * 32 + quad * 8]);

    #pragma unroll
    for (int nt = 0; nt < 8; nt++) {
        f32x4 acc = {0.f, 0.f, 0.f, 0.f};
        #pragma unroll
        for (int ks = 0; ks < 4; ks++) {
            bf16x8 bf = *(const bf16x8*)(&Ws[nt * 16 + m][ks * 32 + quad * 8]);
            acc = __builtin_amdgcn_mfma_f32_16x16x32_bf16(af[ks], bf, acc, 0, 0, 0);
        }
        int f = nt * 16 + m;
        int si = ((f & 63) << 1) | (f >> 6);
        #pragma unroll
        for (int r = 0; r < 4; r++) {
            int row = row0 + wave * 16 + quad * 4 + r;
            if (row < NB) Sup[(size_t)row * AF + si] = f2bf(acc[r]);
        }
    }
}

// ---- bucket histogram (782 buckets of 128 rows) ----
__global__ __launch_bounds__(256) void bhist_kernel(const int* __restrict__ rows,
                                                    int* __restrict__ ghist, int NE, int NBUCK) {
    __shared__ int h[800];
    for (int i = threadIdx.x; i < NBUCK; i += 256) h[i] = 0;
    __syncthreads();
    int stride = gridDim.x * 256;
    for (int e = blockIdx.x * 256 + threadIdx.x; e < NE; e += stride)
        atomicAdd(&h[rows[e] >> 7], 1);
    __syncthreads();
    for (int i = threadIdx.x; i < NBUCK; i += 256)
        if (h[i]) atomicAdd(&ghist[i], h[i]);
}

// ---- exclusive scan of bucket sizes (NBUCK <= 1024, one block) ----
__global__ __launch_bounds__(1024) void bscan_kernel(const int* __restrict__ ghist,
                                                     int* __restrict__ gbase, int NBUCK, int NE) {
    __shared__ int s[1024];
    int tid = threadIdx.x;
    int v = (tid < NBUCK) ? ghist[tid] : 0;
    int x = v;
    s[tid] = x;
    __syncthreads();
    #pragma unroll
    for (int off = 1; off < 1024; off <<= 1) {
        int t = (tid >= off) ? s[tid - off] : 0;
        __syncthreads();
        x += t;
        s[tid] = x;
        __syncthreads();
    }
    if (tid < NBUCK) gbase[tid] = x - v;
    if (tid == 0) gbase[NBUCK] = NE;
}

// ---- passA: place edges into bucket regions, payload = {col | lrow<<17, val} ----
__global__ __launch_bounds__(256) void passA_kernel(const int* __restrict__ rows,
                                                    const int* __restrict__ cols,
                                                    const float* __restrict__ vals,
                                                    const int* __restrict__ gbase,
                                                    int* __restrict__ grel,
                                                    int2* __restrict__ binned, int NE, int NBUCK) {
    __shared__ int h[800];
    __shared__ int rbase[800];
    int tid = threadIdx.x;
    for (int i = tid; i < NBUCK; i += 256) h[i] = 0;
    __syncthreads();
    int base = blockIdx.x * PASSA_CHUNK;
    #pragma unroll
    for (int i = 0; i < PASSA_CHUNK / 256; i++) {
        int e = base + tid + i * 256;
        if (e < NE) atomicAdd(&h[rows[e] >> 7], 1);
    }
    __syncthreads();
    for (int k = tid; k < NBUCK; k += 256) {
        int c = h[k];
        rbase[k] = gbase[k] + (c ? atomicAdd(&grel[k], c) : 0);
        h[k] = 0;
    }
    __syncthreads();
    #pragma unroll
    for (int i = 0; i < PASSA_CHUNK / 256; i++) {
        int e = base + tid + i * 256;
        if (e < NE) {
            int r = rows[e];
            int k = r >> 7;
            int lp = atomicAdd(&h[k], 1);
            int2 p;
            p.x = cols[e] | ((r & 127) << 17);
            p.y = __float_as_int(vals[e]);
            binned[rbase[k] + lp] = p;
        }
    }
}

// ---- fused SpMM: one block per bucket, LDS fp32 out-tile, no global atomics ----
__global__ __launch_bounds__(512) void spmm_kernel(const unsigned short* __restrict__ Sup,
                                                   const int2* __restrict__ binned,
                                                   const int* __restrict__ gbase,
                                                   const float* __restrict__ bias,
                                                   float* __restrict__ out, int NA) {
    __shared__ float tile[BROWS * AF];   // 64 KB
    int tid = threadIdx.x;
    #pragma unroll
    for (int i = tid; i < BROWS * AF / 4; i += 512)
        ((float4*)tile)[i] = make_float4(0.f, 0.f, 0.f, 0.f);
    __syncthreads();
    int b = blockIdx.x;
    int e0 = gbase[b], e1 = gbase[b + 1];
    int lane = tid & 63, wv = tid >> 6;
    int eb = e0 + wv * 64;
    for (; eb + 64 <= e1; eb += 512) {
        int2 p = binned[eb + lane];
        #pragma unroll
        for (int j = 0; j < 64; j += 4) {
            int px0 = __shfl(p.x, j + 0);
            int px1 = __shfl(p.x, j + 1);
            int px2 = __shfl(p.x, j + 2);
            int px3 = __shfl(p.x, j + 3);
            float v0 = __uint_as_float(__shfl(p.y, j + 0));
            float v1 = __uint_as_float(__shfl(p.y, j + 1));
            float v2 = __uint_as_float(__shfl(p.y, j + 2));
            float v3 = __uint_as_float(__shfl(p.y, j + 3));
            unsigned int s0 = *(const unsigned int*)(Sup + (size_t)(px0 & 0x1FFFF) * AF + lane * 2);
            unsigned int s1 = *(const unsigned int*)(Sup + (size_t)(px1 & 0x1FFFF) * AF + lane * 2);
            unsigned int s2 = *(const unsigned int*)(Sup + (size_t)(px2 & 0x1FFFF) * AF + lane * 2);
            unsigned int s3 = *(const unsigned int*)(Sup + (size_t)(px3 & 0x1FFFF) * AF + lane * 2);
            int lr0 = px0 >> 17, lr1 = px1 >> 17, lr2 = px2 >> 17, lr3 = px3 >> 17;
            atomicAdd(&tile[lr0 * AF + lane],      v0 * bflo(s0));
            atomicAdd(&tile[lr0 * AF + 64 + lane], v0 * bfhi(s0));
            atomicAdd(&tile[lr1 * AF + lane],      v1 * bflo(s1));
            atomicAdd(&tile[lr1 * AF + 64 + lane], v1 * bfhi(s1));
            atomicAdd(&tile[lr2 * AF + lane],      v2 * bflo(s2));
            atomicAdd(&tile[lr2 * AF + 64 + lane], v2 * bfhi(s2));
            atomicAdd(&tile[lr3 * AF + lane],      v3 * bflo(s3));
            atomicAdd(&tile[lr3 * AF + 64 + lane], v3 * bfhi(s3));
        }
    }
    if (eb < e1) {  // tail batch (<64 edges), wave-uniform condition
        int n = e1 - eb;
        int2 p = (lane < n) ? binned[eb + lane] : make_int2(0, 0);
        for (int j = 0; j < n; j++) {
            int px = __shfl(p.x, j);
            float v = __uint_as_float(__shfl(p.y, j));
            unsigned int s = *(const unsigned int*)(Sup + (size_t)(px & 0x1FFFF) * AF + lane * 2);
            int lr = px >> 17;
            atomicAdd(&tile[lr * AF + lane],      v * bflo(s));
            atomicAdd(&tile[lr * AF + 64 + lane], v * bfhi(s));
        }
    }
    __syncthreads();
    int row0 = b * BROWS;
    #pragma unroll
    for (int i = tid; i < BROWS * (AF / 4); i += 512) {
        int r = i >> 5, c4 = i & 31;
        int row = row0 + r;
        if (row < NA) {
            float4 t = ((float4*)tile)[i];
            float4 bz = ((const float4*)bias)[c4];
            t.x += bz.x; t.y += bz.y; t.z += bz.z; t.w += bz.w;
            ((float4*)(out + (size_t)row * AF))[c4] = t;
        }
    }
}

extern "C" void kernel_launch(void* const* d_in, const int* in_sizes, int n_in,
                              void* d_out, int out_size, void* d_ws, size_t ws_size,
                              hipStream_t stream) {
    const float* b_input   = (const float*)d_in[0];
    const int*   edge_rows = (const int*)d_in[1];
    const int*   edge_cols = (const int*)d_in[2];
    const float* edge_vals = (const float*)d_in[3];
    const float* a_weight  = (const float*)d_in[4];
    const float* a_bias    = (const float*)d_in[5];
    const int NB = in_sizes[0] / BF;
    const int NE = in_sizes[1];
    const int NA = out_size / AF;
    const int NBUCK = (NA + BROWS - 1) / BROWS;   // 782
    float* out = (float*)d_out;

    // workspace layout (~38.5 MB)
    char* ws = (char*)d_ws;
    size_t off = 0;
    unsigned short* Sup = (unsigned short*)(ws + off); off += (size_t)NB * AF * sizeof(unsigned short);
    unsigned short* Wt  = (unsigned short*)(ws + off); off += (size_t)BF * AF * sizeof(unsigned short);
    int* ghist = (int*)(ws + off); off += 1024 * sizeof(int);
    int* grel  = (int*)(ws + off); off += 1024 * sizeof(int);
    int* gbase = (int*)(ws + off); off += 1032 * sizeof(int);
    int2* binned = (int2*)(ws + off); off += (size_t)NE * sizeof(int2);
    (void)ws_size; (void)n_in;

    hipMemsetAsync(ghist, 0, 2048 * sizeof(int), stream);   // ghist + grel

    wtrans_kernel<<<64, 256, 0, stream>>>(a_weight, Wt);
    gemm_mfma_kernel<<<(NB + 63) / 64, 256, 0, stream>>>(b_input, Wt, Sup, NB);
    bhist_kernel<<<391, 256, 0, stream>>>(edge_rows, ghist, NE, NBUCK);
    bscan_kernel<<<1, 1024, 0, stream>>>(ghist, gbase, NBUCK, NE);
    passA_kernel<<<(NE + PASSA_CHUNK - 1) / PASSA_CHUNK, 256, 0, stream>>>(
        edge_rows, edge_cols, edge_vals, gbase, grel, binned, NE, NBUCK);
    spmm_kernel<<<NBUCK, 512, 0, stream>>>(Sup, binned, gbase, a_bias, out, NA);
}

// Round 4
// 274.342 us; speedup vs baseline: 5.7296x; 5.7296x over previous
//
#include <hip/hip_runtime.h>
#include <hip/hip_bf16.h>

#define AF 128
#define BF 128
#define BROWS 128            // rows per bucket
#define CAP 3072             // slots per bucket region (mean 2046, sigma 45 -> safe)
#define PASSA_CHUNK 8192
#define NBUCK_MAX 800

typedef __attribute__((ext_vector_type(8))) short bf16x8;
typedef __attribute__((ext_vector_type(4))) float f32x4;

__device__ inline unsigned short f2bf(float f) {
    unsigned int u = __float_as_uint(f);
    u += 0x7FFF + ((u >> 16) & 1);          // round-to-nearest-even
    return (unsigned short)(u >> 16);
}
__device__ inline unsigned int pk2bf(float x, float y) {
    __hip_bfloat162 h = __float22bfloat162_rn(make_float2(x, y));
    return *(unsigned int*)&h;
}
__device__ inline float bflo(unsigned int u) { return __uint_as_float(u << 16); }
__device__ inline float bfhi(unsigned int u) { return __uint_as_float(u & 0xFFFF0000u); }

// ---- one-time: Wt[n][k] = bf16(W[k][n]), 128x128 ----
__global__ void wtrans_kernel(const float* __restrict__ W, unsigned short* __restrict__ Wt) {
    int idx = blockIdx.x * 256 + threadIdx.x;   // grid 64 x 256
    int n = idx & 127, k = idx >> 7;
    Wt[n * 128 + k] = f2bf(W[(size_t)k * 128 + n]);
}

// ---- MFMA GEMM: Sup[NB][128] bf16 = Bin @ W, stored interleaved:
//      Sup[row*128 + 2*(f&63) + (f>>6)]  so uint at short-offset lane*2 = feats (lane, lane+64)
__global__ __launch_bounds__(256) void gemm_mfma_kernel(const float* __restrict__ Bin,
                                                        const unsigned short* __restrict__ Wt,
                                                        unsigned short* __restrict__ Sup, int NB) {
    __shared__ unsigned short As[64][136];
    __shared__ unsigned short Ws[128][136];
    const int tid = threadIdx.x;
    const int lane = tid & 63;
    const int wave = tid >> 6;
    const int row0 = blockIdx.x * 64;

    {   // stage A tile (fp32 -> bf16 packed): 4 threads per row, 32 floats each
        int lr = tid >> 2;
        int ks = (tid & 3) * 32;
        int gr = row0 + lr;
        const float4* src = (const float4*)(Bin + (size_t)gr * BF + ks);
        #pragma unroll
        for (int i = 0; i < 4; i++) {
            float4 a = (gr < NB) ? src[2 * i]     : make_float4(0.f, 0.f, 0.f, 0.f);
            float4 b = (gr < NB) ? src[2 * i + 1] : make_float4(0.f, 0.f, 0.f, 0.f);
            uint4 u;
            u.x = pk2bf(a.x, a.y); u.y = pk2bf(a.z, a.w);
            u.z = pk2bf(b.x, b.y); u.w = pk2bf(b.z, b.w);
            *(uint4*)(&As[lr][ks + i * 8]) = u;
        }
    }
    {   // stage Wt (already bf16): thread copies 128 B
        int r = tid >> 1;
        int c = (tid & 1) * 64;
        const uint4* src = (const uint4*)(Wt + r * 128 + c);
        uint4* dst = (uint4*)(&Ws[r][c]);
        #pragma unroll
        for (int i = 0; i < 8; i++) dst[i] = src[i];
    }
    __syncthreads();

    const int m = lane & 15;
    const int quad = lane >> 4;

    bf16x8 af[4];
    #pragma unroll
    for (int ks = 0; ks < 4; ks++)
        af[ks] = *(const bf16x8*)(&As[wave * 16 + m][ks * 32 + quad * 8]);

    #pragma unroll
    for (int nt = 0; nt < 8; nt++) {
        f32x4 acc = {0.f, 0.f, 0.f, 0.f};
        #pragma unroll
        for (int ks = 0; ks < 4; ks++) {
            bf16x8 bf = *(const bf16x8*)(&Ws[nt * 16 + m][ks * 32 + quad * 8]);
            acc = __builtin_amdgcn_mfma_f32_16x16x32_bf16(af[ks], bf, acc, 0, 0, 0);
        }
        int f = nt * 16 + m;
        int si = ((f & 63) << 1) | (f >> 6);
        #pragma unroll
        for (int r = 0; r < 4; r++) {
            int row = row0 + wave * 16 + quad * 4 + r;
            if (row < NB) Sup[(size_t)row * AF + si] = f2bf(acc[r]);
        }
    }
}

// ---- passA: bin edges into fixed-stride bucket regions; payload {col | lrow<<17, val} ----
__global__ __launch_bounds__(256) void passA_kernel(const int* __restrict__ rows,
                                                    const int* __restrict__ cols,
                                                    const float* __restrict__ vals,
                                                    int* __restrict__ grel,
                                                    int2* __restrict__ binned, int NE, int NBUCK) {
    __shared__ int h[NBUCK_MAX];
    __shared__ int rbase[NBUCK_MAX];
    int tid = threadIdx.x;
    for (int i = tid; i < NBUCK; i += 256) h[i] = 0;
    __syncthreads();
    int base = blockIdx.x * PASSA_CHUNK;
    #pragma unroll
    for (int i = 0; i < PASSA_CHUNK / 256; i++) {
        int e = base + tid + i * 256;
        if (e < NE) atomicAdd(&h[rows[e] >> 7], 1);
    }
    __syncthreads();
    for (int k = tid; k < NBUCK; k += 256) {
        int c = h[k];
        rbase[k] = k * CAP + (c ? atomicAdd(&grel[k], c) : 0);
        h[k] = 0;
    }
    __syncthreads();
    #pragma unroll
    for (int i = 0; i < PASSA_CHUNK / 256; i++) {
        int e = base + tid + i * 256;
        if (e < NE) {
            int r = rows[e];
            int k = r >> 7;
            int lp = atomicAdd(&h[k], 1);
            int2 p;
            p.x = cols[e] | ((r & 127) << 17);
            p.y = __float_as_int(vals[e]);
            binned[rbase[k] + lp] = p;
        }
    }
}

// ---- fused per-bucket sort (int LDS atomics) + atomic-free gather ----
__global__ __launch_bounds__(256) void spmm_sorted_kernel(const unsigned short* __restrict__ Sup,
                                                          const int2* __restrict__ binned,
                                                          const int* __restrict__ grel,
                                                          const float* __restrict__ bias,
                                                          float* __restrict__ out, int NA) {
    __shared__ int   spx[CAP];      // sorted cols (12 KB)
    __shared__ float spy[CAP];      // sorted vals (12 KB)
    __shared__ int cnt[BROWS];
    __shared__ int sc[BROWS];
    __shared__ int rs[BROWS + 1];
    __shared__ int cur[BROWS];
    const int tid = threadIdx.x;
    const int b = blockIdx.x;
    int n = grel[b]; if (n > CAP) n = CAP;
    const int2* src = binned + (size_t)b * CAP;

    if (tid < BROWS) cnt[tid] = 0;
    __syncthreads();
    // pass 1: histogram of local rows (int LDS atomics -> native ds ops)
    for (int i = tid; i < n; i += 256)
        atomicAdd(&cnt[(src[i].x >> 17) & 127], 1);
    __syncthreads();
    // block scan over 128 entries
    int v = (tid < BROWS) ? cnt[tid] : 0;
    int x = v;
    if (tid < BROWS) sc[tid] = x;
    __syncthreads();
    #pragma unroll
    for (int off = 1; off < BROWS; off <<= 1) {
        int t = (tid < BROWS && tid >= off) ? sc[tid - off] : 0;
        __syncthreads();
        if (tid < BROWS) { x += t; sc[tid] = x; }
        __syncthreads();
    }
    if (tid < BROWS) { rs[tid] = x - v; cur[tid] = x - v; }
    if (tid == BROWS - 1) rs[BROWS] = x;
    __syncthreads();
    // pass 2: scatter into LDS-sorted arrays (src re-read is L2-hot)
    for (int i = tid; i < n; i += 256) {
        int2 p = src[i];
        int lr = (p.x >> 17) & 127;
        int pos = atomicAdd(&cur[lr], 1);
        spx[pos] = p.x & 0x1FFFF;
        spy[pos] = __int_as_float(p.y);
    }
    __syncthreads();

    // gather: wave wv handles rows wv, wv+4, ... ; lane = feats (lane, lane+64)
    const int lane = tid & 63;
    const int wv = tid >> 6;
    const float b0 = bias[lane];
    const float b1 = bias[64 + lane];
    for (int lr = wv; lr < BROWS; lr += 4) {
        int row = b * BROWS + lr;
        if (row >= NA) break;               // rows ascend per wave; wave-uniform
        int e = rs[lr], end = rs[lr + 1];
        float ax = 0.f, ay = 0.f;
        for (; e + 8 <= end; e += 8) {
            int c0 = spx[e],     c1 = spx[e + 1], c2 = spx[e + 2], c3 = spx[e + 3];
            int c4 = spx[e + 4], c5 = spx[e + 5], c6 = spx[e + 6], c7 = spx[e + 7];
            float v0 = spy[e],     v1 = spy[e + 1], v2 = spy[e + 2], v3 = spy[e + 3];
            float v4 = spy[e + 4], v5 = spy[e + 5], v6 = spy[e + 6], v7 = spy[e + 7];
            unsigned int s0 = *(const unsigned int*)(Sup + (size_t)c0 * AF + lane * 2);
            unsigned int s1 = *(const unsigned int*)(Sup + (size_t)c1 * AF + lane * 2);
            unsigned int s2 = *(const unsigned int*)(Sup + (size_t)c2 * AF + lane * 2);
            unsigned int s3 = *(const unsigned int*)(Sup + (size_t)c3 * AF + lane * 2);
            unsigned int s4 = *(const unsigned int*)(Sup + (size_t)c4 * AF + lane * 2);
            unsigned int s5 = *(const unsigned int*)(Sup + (size_t)c5 * AF + lane * 2);
            unsigned int s6 = *(const unsigned int*)(Sup + (size_t)c6 * AF + lane * 2);
            unsigned int s7 = *(const unsigned int*)(Sup + (size_t)c7 * AF + lane * 2);
            ax += v0 * bflo(s0) + v1 * bflo(s1) + v2 * bflo(s2) + v3 * bflo(s3)
                + v4 * bflo(s4) + v5 * bflo(s5) + v6 * bflo(s6) + v7 * bflo(s7);
            ay += v0 * bfhi(s0) + v1 * bfhi(s1) + v2 * bfhi(s2) + v3 * bfhi(s3)
                + v4 * bfhi(s4) + v5 * bfhi(s5) + v6 * bfhi(s6) + v7 * bfhi(s7);
        }
        for (; e < end; e++) {
            int c = spx[e];
            float vv = spy[e];
            unsigned int s = *(const unsigned int*)(Sup + (size_t)c * AF + lane * 2);
            ax += vv * bflo(s);
            ay += vv * bfhi(s);
        }
        out[(size_t)row * AF + lane]      = ax + b0;
        out[(size_t)row * AF + 64 + lane] = ay + b1;
    }
}

extern "C" void kernel_launch(void* const* d_in, const int* in_sizes, int n_in,
                              void* d_out, int out_size, void* d_ws, size_t ws_size,
                              hipStream_t stream) {
    const float* b_input   = (const float*)d_in[0];
    const int*   edge_rows = (const int*)d_in[1];
    const int*   edge_cols = (const int*)d_in[2];
    const float* edge_vals = (const float*)d_in[3];
    const float* a_weight  = (const float*)d_in[4];
    const float* a_bias    = (const float*)d_in[5];
    const int NB = in_sizes[0] / BF;
    const int NE = in_sizes[1];
    const int NA = out_size / AF;
    const int NBUCK = (NA + BROWS - 1) / BROWS;   // 782
    float* out = (float*)d_out;

    // workspace layout (~45 MB)
    char* ws = (char*)d_ws;
    size_t off = 0;
    unsigned short* Sup = (unsigned short*)(ws + off); off += (size_t)NB * AF * sizeof(unsigned short);
    unsigned short* Wt  = (unsigned short*)(ws + off); off += (size_t)BF * AF * sizeof(unsigned short);
    int* grel = (int*)(ws + off); off += 1024 * sizeof(int);
    int2* binned = (int2*)(ws + off); off += (size_t)NBUCK * CAP * sizeof(int2);
    (void)ws_size; (void)n_in;

    hipMemsetAsync(grel, 0, 1024 * sizeof(int), stream);

    wtrans_kernel<<<64, 256, 0, stream>>>(a_weight, Wt);
    gemm_mfma_kernel<<<(NB + 63) / 64, 256, 0, stream>>>(b_input, Wt, Sup, NB);
    passA_kernel<<<(NE + PASSA_CHUNK - 1) / PASSA_CHUNK, 256, 0, stream>>>(
        edge_rows, edge_cols, edge_vals, grel, binned, NE, NBUCK);
    spmm_sorted_kernel<<<NBUCK, 256, 0, stream>>>(Sup, binned, grel, a_bias, out, NA);
}

// Round 5
// 260.371 us; speedup vs baseline: 6.0370x; 1.0537x over previous
//
#include <hip/hip_runtime.h>
#include <hip/hip_bf16.h>

#define AF 128
#define BF 128
#define BROWS 64             // rows per bucket
#define CAP 1600             // slots per bucket (mean 1024, sigma 32 -> +18 sigma)
#define PASSA_CHUNK 8192
#define NBUCK_MAX 1600

typedef __attribute__((ext_vector_type(8))) short bf16x8;
typedef __attribute__((ext_vector_type(4))) float f32x4;

__device__ inline unsigned short f2bf(float f) {
    unsigned int u = __float_as_uint(f);
    u += 0x7FFF + ((u >> 16) & 1);          // round-to-nearest-even
    return (unsigned short)(u >> 16);
}
__device__ inline unsigned int pk2bf(float x, float y) {
    __hip_bfloat162 h = __float22bfloat162_rn(make_float2(x, y));
    return *(unsigned int*)&h;
}
__device__ inline float bflo(unsigned int u) { return __uint_as_float(u << 16); }
__device__ inline float bfhi(unsigned int u) { return __uint_as_float(u & 0xFFFF0000u); }

// ---- one-time: Wt[n][k] = bf16(W[k][n]), 128x128 ----
__global__ void wtrans_kernel(const float* __restrict__ W, unsigned short* __restrict__ Wt) {
    int idx = blockIdx.x * 256 + threadIdx.x;   // grid 64 x 256
    int n = idx & 127, k = idx >> 7;
    Wt[n * 128 + k] = f2bf(W[(size_t)k * 128 + n]);
}

// ---- MFMA GEMM: Sup[NB][128] bf16 = Bin @ W, stored interleaved:
//      Sup[row*128 + 2*(f&63) + (f>>6)]  so uint at short-offset lane*2 = feats (lane, lane+64)
__global__ __launch_bounds__(256) void gemm_mfma_kernel(const float* __restrict__ Bin,
                                                        const unsigned short* __restrict__ Wt,
                                                        unsigned short* __restrict__ Sup, int NB) {
    __shared__ unsigned short As[64][136];
    __shared__ unsigned short Ws[128][136];
    const int tid = threadIdx.x;
    const int lane = tid & 63;
    const int wave = tid >> 6;
    const int row0 = blockIdx.x * 64;

    {   // stage A tile (fp32 -> bf16 packed): 4 threads per row, 32 floats each
        int lr = tid >> 2;
        int ks = (tid & 3) * 32;
        int gr = row0 + lr;
        const float4* src = (const float4*)(Bin + (size_t)gr * BF + ks);
        #pragma unroll
        for (int i = 0; i < 4; i++) {
            float4 a = (gr < NB) ? src[2 * i]     : make_float4(0.f, 0.f, 0.f, 0.f);
            float4 b = (gr < NB) ? src[2 * i + 1] : make_float4(0.f, 0.f, 0.f, 0.f);
            uint4 u;
            u.x = pk2bf(a.x, a.y); u.y = pk2bf(a.z, a.w);
            u.z = pk2bf(b.x, b.y); u.w = pk2bf(b.z, b.w);
            *(uint4*)(&As[lr][ks + i * 8]) = u;
        }
    }
    {   // stage Wt (already bf16): thread copies 128 B
        int r = tid >> 1;
        int c = (tid & 1) * 64;
        const uint4* src = (const uint4*)(Wt + r * 128 + c);
        uint4* dst = (uint4*)(&Ws[r][c]);
        #pragma unroll
        for (int i = 0; i < 8; i++) dst[i] = src[i];
    }
    __syncthreads();

    const int m = lane & 15;
    const int quad = lane >> 4;

    bf16x8 af[4];
    #pragma unroll
    for (int ks = 0; ks < 4; ks++)
        af[ks] = *(const bf16x8*)(&As[wave * 16 + m][ks * 32 + quad * 8]);

    #pragma unroll
    for (int nt = 0; nt < 8; nt++) {
        f32x4 acc = {0.f, 0.f, 0.f, 0.f};
        #pragma unroll
        for (int ks = 0; ks < 4; ks++) {
            bf16x8 bf = *(const bf16x8*)(&Ws[nt * 16 + m][ks * 32 + quad * 8]);
            acc = __builtin_amdgcn_mfma_f32_16x16x32_bf16(af[ks], bf, acc, 0, 0, 0);
        }
        int f = nt * 16 + m;
        int si = ((f & 63) << 1) | (f >> 6);
        #pragma unroll
        for (int r = 0; r < 4; r++) {
            int row = row0 + wave * 16 + quad * 4 + r;
            if (row < NB) Sup[(size_t)row * AF + si] = f2bf(acc[r]);
        }
    }
}

// ---- passA: bin edges into fixed-stride bucket regions; payload {col | lrow<<17, val} ----
__global__ __launch_bounds__(256) void passA_kernel(const int* __restrict__ rows,
                                                    const int* __restrict__ cols,
                                                    const float* __restrict__ vals,
                                                    int* __restrict__ grel,
                                                    int2* __restrict__ binned, int NE, int NBUCK) {
    __shared__ int h[NBUCK_MAX];
    __shared__ int rbase[NBUCK_MAX];
    int tid = threadIdx.x;
    for (int i = tid; i < NBUCK; i += 256) h[i] = 0;
    __syncthreads();
    int base = blockIdx.x * PASSA_CHUNK;
    #pragma unroll
    for (int i = 0; i < PASSA_CHUNK / 256; i++) {
        int e = base + tid + i * 256;
        if (e < NE) atomicAdd(&h[rows[e] >> 6], 1);
    }
    __syncthreads();
    for (int k = tid; k < NBUCK; k += 256) {
        int c = h[k];
        rbase[k] = k * CAP + (c ? atomicAdd(&grel[k], c) : 0);
        h[k] = 0;
    }
    __syncthreads();
    #pragma unroll
    for (int i = 0; i < PASSA_CHUNK / 256; i++) {
        int e = base + tid + i * 256;
        if (e < NE) {
            int r = rows[e];
            int k = r >> 6;
            int lp = atomicAdd(&h[k], 1);
            int2 p;
            p.x = cols[e] | ((r & 63) << 17);
            p.y = __float_as_int(vals[e]);
            binned[rbase[k] + lp] = p;
        }
    }
}

// ---- fused per-bucket sort (int LDS atomics) + atomic-free gather; 512 thr, 64 rows ----
__global__ __launch_bounds__(512) void spmm_sorted_kernel(const unsigned short* __restrict__ Sup,
                                                          const int2* __restrict__ binned,
                                                          const int* __restrict__ grel,
                                                          const float* __restrict__ bias,
                                                          float* __restrict__ out, int NA) {
    __shared__ int   spx[CAP];      // sorted cols (6.4 KB)
    __shared__ float spy[CAP];      // sorted vals (6.4 KB)
    __shared__ int cnt[BROWS];
    __shared__ int sc[BROWS];
    __shared__ int rs[BROWS + 1];
    __shared__ int cur[BROWS];
    const int tid = threadIdx.x;
    const int b = blockIdx.x;
    int n = grel[b]; if (n > CAP) n = CAP;
    const int2* src = binned + (size_t)b * CAP;

    // single global read: stage this block's edges into registers
    int2 pr[4];
    #pragma unroll
    for (int j = 0; j < 4; j++) {
        int i = tid + j * 512;
        pr[j] = (i < n) ? src[i] : make_int2(-1, 0);
    }
    if (tid < BROWS) cnt[tid] = 0;
    __syncthreads();
    // pass 1: histogram of local rows (native int LDS atomics)
    #pragma unroll
    for (int j = 0; j < 4; j++)
        if (pr[j].x >= 0) atomicAdd(&cnt[(pr[j].x >> 17) & 63], 1);
    __syncthreads();
    // block scan over 64 entries
    int v = (tid < BROWS) ? cnt[tid] : 0;
    int x = v;
    if (tid < BROWS) sc[tid] = x;
    __syncthreads();
    #pragma unroll
    for (int off = 1; off < BROWS; off <<= 1) {
        int t = (tid < BROWS && tid >= off) ? sc[tid - off] : 0;
        __syncthreads();
        if (tid < BROWS) { x += t; sc[tid] = x; }
        __syncthreads();
    }
    if (tid < BROWS) { rs[tid] = x - v; cur[tid] = x - v; }
    if (tid == BROWS - 1) rs[BROWS] = x;
    __syncthreads();
    // pass 2: scatter from registers into LDS-sorted arrays
    #pragma unroll
    for (int j = 0; j < 4; j++) {
        if (pr[j].x >= 0) {
            int lr = (pr[j].x >> 17) & 63;
            int pos = atomicAdd(&cur[lr], 1);
            spx[pos] = pr[j].x & 0x1FFFF;
            spy[pos] = __int_as_float(pr[j].y);
        }
    }
    __syncthreads();

    // gather: wave wv handles rows wv, wv+8, ...; lane = feats (lane, lane+64)
    const int lane = tid & 63;
    const int wv = tid >> 6;
    const float b0 = bias[lane];
    const float b1 = bias[64 + lane];
    for (int lr = wv; lr < BROWS; lr += 8) {
        int row = b * BROWS + lr;
        if (row >= NA) break;               // rows ascend per wave; wave-uniform
        int e = rs[lr], end = rs[lr + 1];
        float ax = 0.f, ay = 0.f;
        for (; e + 8 <= end; e += 8) {
            int c0 = spx[e],     c1 = spx[e + 1], c2 = spx[e + 2], c3 = spx[e + 3];
            int c4 = spx[e + 4], c5 = spx[e + 5], c6 = spx[e + 6], c7 = spx[e + 7];
            float v0 = spy[e],     v1 = spy[e + 1], v2 = spy[e + 2], v3 = spy[e + 3];
            float v4 = spy[e + 4], v5 = spy[e + 5], v6 = spy[e + 6], v7 = spy[e + 7];
            unsigned int s0 = *(const unsigned int*)(Sup + (size_t)c0 * AF + lane * 2);
            unsigned int s1 = *(const unsigned int*)(Sup + (size_t)c1 * AF + lane * 2);
            unsigned int s2 = *(const unsigned int*)(Sup + (size_t)c2 * AF + lane * 2);
            unsigned int s3 = *(const unsigned int*)(Sup + (size_t)c3 * AF + lane * 2);
            unsigned int s4 = *(const unsigned int*)(Sup + (size_t)c4 * AF + lane * 2);
            unsigned int s5 = *(const unsigned int*)(Sup + (size_t)c5 * AF + lane * 2);
            unsigned int s6 = *(const unsigned int*)(Sup + (size_t)c6 * AF + lane * 2);
            unsigned int s7 = *(const unsigned int*)(Sup + (size_t)c7 * AF + lane * 2);
            ax += v0 * bflo(s0) + v1 * bflo(s1) + v2 * bflo(s2) + v3 * bflo(s3)
                + v4 * bflo(s4) + v5 * bflo(s5) + v6 * bflo(s6) + v7 * bflo(s7);
            ay += v0 * bfhi(s0) + v1 * bfhi(s1) + v2 * bfhi(s2) + v3 * bfhi(s3)
                + v4 * bfhi(s4) + v5 * bfhi(s5) + v6 * bfhi(s6) + v7 * bfhi(s7);
        }
        for (; e < end; e++) {
            int c = spx[e];
            float vv = spy[e];
            unsigned int s = *(const unsigned int*)(Sup + (size_t)c * AF + lane * 2);
            ax += vv * bflo(s);
            ay += vv * bfhi(s);
        }
        out[(size_t)row * AF + lane]      = ax + b0;
        out[(size_t)row * AF + 64 + lane] = ay + b1;
    }
}

extern "C" void kernel_launch(void* const* d_in, const int* in_sizes, int n_in,
                              void* d_out, int out_size, void* d_ws, size_t ws_size,
                              hipStream_t stream) {
    const float* b_input   = (const float*)d_in[0];
    const int*   edge_rows = (const int*)d_in[1];
    const int*   edge_cols = (const int*)d_in[2];
    const float* edge_vals = (const float*)d_in[3];
    const float* a_weight  = (const float*)d_in[4];
    const float* a_bias    = (const float*)d_in[5];
    const int NB = in_sizes[0] / BF;
    const int NE = in_sizes[1];
    const int NA = out_size / AF;
    const int NBUCK = (NA + BROWS - 1) / BROWS;   // 1563
    float* out = (float*)d_out;

    // workspace layout (~46 MB)
    char* ws = (char*)d_ws;
    size_t off = 0;
    unsigned short* Sup = (unsigned short*)(ws + off); off += (size_t)NB * AF * sizeof(unsigned short);
    unsigned short* Wt  = (unsigned short*)(ws + off); off += (size_t)BF * AF * sizeof(unsigned short);
    int* grel = (int*)(ws + off); off += 2048 * sizeof(int);
    int2* binned = (int2*)(ws + off); off += (size_t)NBUCK * CAP * sizeof(int2);
    (void)ws_size; (void)n_in;

    hipMemsetAsync(grel, 0, 2048 * sizeof(int), stream);

    wtrans_kernel<<<64, 256, 0, stream>>>(a_weight, Wt);
    gemm_mfma_kernel<<<(NB + 63) / 64, 256, 0, stream>>>(b_input, Wt, Sup, NB);
    passA_kernel<<<(NE + PASSA_CHUNK - 1) / PASSA_CHUNK, 256, 0, stream>>>(
        edge_rows, edge_cols, edge_vals, grel, binned, NE, NBUCK);
    spmm_sorted_kernel<<<NBUCK, 512, 0, stream>>>(Sup, binned, grel, a_bias, out, NA);
}

// Round 6
// 241.726 us; speedup vs baseline: 6.5027x; 1.0771x over previous
//
#include <hip/hip_runtime.h>
#include <hip/hip_bf16.h>

#define AF 128
#define BF 128
#define BROWS 64             // rows per fine bucket
#define CAP_F 1600           // slots per fine bucket (mean 1024, sigma 32)
#define CROWS 1024           // rows per coarse bucket (= 16 fine)
#define CAP_C 18432          // slots per coarse bucket (mean 16384, sigma 128)
#define CHUNK1 2048
#define NCOARSE_MAX 128

typedef __attribute__((ext_vector_type(8))) short bf16x8;
typedef __attribute__((ext_vector_type(4))) float f32x4;

__device__ inline unsigned short f2bf(float f) {
    unsigned int u = __float_as_uint(f);
    u += 0x7FFF + ((u >> 16) & 1);          // round-to-nearest-even
    return (unsigned short)(u >> 16);
}
__device__ inline unsigned int pk2bf(float x, float y) {
    __hip_bfloat162 h = __float22bfloat162_rn(make_float2(x, y));
    return *(unsigned int*)&h;
}
__device__ inline float bflo(unsigned int u) { return __uint_as_float(u << 16); }
__device__ inline float bfhi(unsigned int u) { return __uint_as_float(u & 0xFFFF0000u); }

// ---- one-time: Wt[n][k] = bf16(W[k][n]), 128x128 ----
__global__ void wtrans_kernel(const float* __restrict__ W, unsigned short* __restrict__ Wt) {
    int idx = blockIdx.x * 256 + threadIdx.x;   // grid 64 x 256
    int n = idx & 127, k = idx >> 7;
    Wt[n * 128 + k] = f2bf(W[(size_t)k * 128 + n]);
}

// ---- MFMA GEMM: Sup[NB][128] bf16 = Bin @ W, stored interleaved:
//      Sup[row*128 + 2*(f&63) + (f>>6)]  so uint at short-offset lane*2 = feats (lane, lane+64)
__global__ __launch_bounds__(256) void gemm_mfma_kernel(const float* __restrict__ Bin,
                                                        const unsigned short* __restrict__ Wt,
                                                        unsigned short* __restrict__ Sup, int NB) {
    __shared__ unsigned short As[64][136];
    __shared__ unsigned short Ws[128][136];
    const int tid = threadIdx.x;
    const int lane = tid & 63;
    const int wave = tid >> 6;
    const int row0 = blockIdx.x * 64;

    {   // stage A tile (fp32 -> bf16 packed): 4 threads per row, 32 floats each
        int lr = tid >> 2;
        int ks = (tid & 3) * 32;
        int gr = row0 + lr;
        const float4* src = (const float4*)(Bin + (size_t)gr * BF + ks);
        #pragma unroll
        for (int i = 0; i < 4; i++) {
            float4 a = (gr < NB) ? src[2 * i]     : make_float4(0.f, 0.f, 0.f, 0.f);
            float4 b = (gr < NB) ? src[2 * i + 1] : make_float4(0.f, 0.f, 0.f, 0.f);
            uint4 u;
            u.x = pk2bf(a.x, a.y); u.y = pk2bf(a.z, a.w);
            u.z = pk2bf(b.x, b.y); u.w = pk2bf(b.z, b.w);
            *(uint4*)(&As[lr][ks + i * 8]) = u;
        }
    }
    {   // stage Wt (already bf16): thread copies 128 B
        int r = tid >> 1;
        int c = (tid & 1) * 64;
        const uint4* src = (const uint4*)(Wt + r * 128 + c);
        uint4* dst = (uint4*)(&Ws[r][c]);
        #pragma unroll
        for (int i = 0; i < 8; i++) dst[i] = src[i];
    }
    __syncthreads();

    const int m = lane & 15;
    const int quad = lane >> 4;

    bf16x8 af[4];
    #pragma unroll
    for (int ks = 0; ks < 4; ks++)
        af[ks] = *(const bf16x8*)(&As[wave * 16 + m][ks * 32 + quad * 8]);

    #pragma unroll
    for (int nt = 0; nt < 8; nt++) {
        f32x4 acc = {0.f, 0.f, 0.f, 0.f};
        #pragma unroll
        for (int ks = 0; ks < 4; ks++) {
            bf16x8 bf = *(const bf16x8*)(&Ws[nt * 16 + m][ks * 32 + quad * 8]);
            acc = __builtin_amdgcn_mfma_f32_16x16x32_bf16(af[ks], bf, acc, 0, 0, 0);
        }
        int f = nt * 16 + m;
        int si = ((f & 63) << 1) | (f >> 6);
        #pragma unroll
        for (int r = 0; r < 4; r++) {
            int row = row0 + wave * 16 + quad * 4 + r;
            if (row < NB) Sup[(size_t)row * AF + si] = f2bf(acc[r]);
        }
    }
}

// ---- passA1: bin edges into 98 coarse regions; payload {col | lrow10<<17, val} ----
__global__ __launch_bounds__(256) void passA1_kernel(const int* __restrict__ rows,
                                                     const int* __restrict__ cols,
                                                     const float* __restrict__ vals,
                                                     int* __restrict__ grelC,
                                                     int2* __restrict__ binnedC, int NE, int NCOARSE) {
    __shared__ int h[NCOARSE_MAX];
    __shared__ int rbase[NCOARSE_MAX];
    int tid = threadIdx.x;
    if (tid < NCOARSE) h[tid] = 0;
    __syncthreads();
    int base = blockIdx.x * CHUNK1;
    #pragma unroll
    for (int i = 0; i < CHUNK1 / 256; i++) {
        int e = base + tid + i * 256;
        if (e < NE) atomicAdd(&h[rows[e] >> 10], 1);
    }
    __syncthreads();
    if (tid < NCOARSE) {
        int c = h[tid];
        rbase[tid] = tid * CAP_C + (c ? atomicAdd(&grelC[tid], c) : 0);
        h[tid] = 0;
    }
    __syncthreads();
    #pragma unroll
    for (int i = 0; i < CHUNK1 / 256; i++) {
        int e = base + tid + i * 256;
        if (e < NE) {
            int r = rows[e];
            int k = r >> 10;
            int lp = atomicAdd(&h[k], 1);
            int2 p;
            p.x = cols[e] | ((r & 1023) << 17);
            p.y = __float_as_int(vals[e]);
            binnedC[rbase[k] + lp] = p;
        }
    }
}

// ---- passA2: 8 blocks per coarse bucket -> scatter into 16 fine buckets each ----
__global__ __launch_bounds__(256) void passA2_kernel(const int2* __restrict__ binnedC,
                                                     const int* __restrict__ grelC,
                                                     int* __restrict__ grelF,
                                                     int2* __restrict__ binnedF, int NBUCK) {
    __shared__ int h[16];
    __shared__ int rb[16];
    const int tid = threadIdx.x;
    const int j = blockIdx.x >> 3;      // coarse bucket
    const int s = blockIdx.x & 7;       // slice
    int n = grelC[j]; if (n > CAP_C) n = CAP_C;
    const int st = (n * s) >> 3;
    const int en = (n * (s + 1)) >> 3;
    const int2* src = binnedC + (size_t)j * CAP_C;
    if (tid < 16) h[tid] = 0;
    __syncthreads();
    for (int i = st + tid; i < en; i += 256)
        atomicAdd(&h[src[i].x >> 23], 1);
    __syncthreads();
    if (tid < 16) {
        int c = h[tid];
        int fine = j * 16 + tid;
        rb[tid] = (fine < NBUCK) ? (fine * CAP_F + (c ? atomicAdd(&grelF[fine], c) : 0)) : 0;
        h[tid] = 0;
    }
    __syncthreads();
    for (int i = st + tid; i < en; i += 256) {
        int2 p = src[i];
        int sub = p.x >> 23;
        int lp = atomicAdd(&h[sub], 1);
        int2 q;
        q.x = p.x & 0x7FFFFF;           // col | lrow6<<17
        q.y = p.y;
        binnedF[(size_t)rb[sub] + lp] = q;
    }
}

// ---- fused per-bucket sort (int LDS atomics) + atomic-free gather; 512 thr, 64 rows ----
__global__ __launch_bounds__(512) void spmm_sorted_kernel(const unsigned short* __restrict__ Sup,
                                                          const int2* __restrict__ binned,
                                                          const int* __restrict__ grel,
                                                          const float* __restrict__ bias,
                                                          float* __restrict__ out, int NA) {
    __shared__ int   spx[CAP_F];
    __shared__ float spy[CAP_F];
    __shared__ int cnt[BROWS];
    __shared__ int sc[BROWS];
    __shared__ int rs[BROWS + 1];
    __shared__ int cur[BROWS];
    const int tid = threadIdx.x;
    const int b = blockIdx.x;
    int n = grel[b]; if (n > CAP_F) n = CAP_F;
    const int2* src = binned + (size_t)b * CAP_F;

    // single global read: stage this block's edges into registers
    int2 pr[4];
    #pragma unroll
    for (int j = 0; j < 4; j++) {
        int i = tid + j * 512;
        pr[j] = (i < n) ? src[i] : make_int2(-1, 0);
    }
    if (tid < BROWS) cnt[tid] = 0;
    __syncthreads();
    #pragma unroll
    for (int j = 0; j < 4; j++)
        if (pr[j].x >= 0) atomicAdd(&cnt[(pr[j].x >> 17) & 63], 1);
    __syncthreads();
    int v = (tid < BROWS) ? cnt[tid] : 0;
    int x = v;
    if (tid < BROWS) sc[tid] = x;
    __syncthreads();
    #pragma unroll
    for (int off = 1; off < BROWS; off <<= 1) {
        int t = (tid < BROWS && tid >= off) ? sc[tid - off] : 0;
        __syncthreads();
        if (tid < BROWS) { x += t; sc[tid] = x; }
        __syncthreads();
    }
    if (tid < BROWS) { rs[tid] = x - v; cur[tid] = x - v; }
    if (tid == BROWS - 1) rs[BROWS] = x;
    __syncthreads();
    #pragma unroll
    for (int j = 0; j < 4; j++) {
        if (pr[j].x >= 0) {
            int lr = (pr[j].x >> 17) & 63;
            int pos = atomicAdd(&cur[lr], 1);
            spx[pos] = pr[j].x & 0x1FFFF;
            spy[pos] = __int_as_float(pr[j].y);
        }
    }
    __syncthreads();

    const int lane = tid & 63;
    const int wv = tid >> 6;
    const float b0 = bias[lane];
    const float b1 = bias[64 + lane];
    for (int lr = wv; lr < BROWS; lr += 8) {
        int row = b * BROWS + lr;
        if (row >= NA) break;
        int e = rs[lr], end = rs[lr + 1];
        float ax = 0.f, ay = 0.f;
        for (; e + 8 <= end; e += 8) {
            int c0 = spx[e],     c1 = spx[e + 1], c2 = spx[e + 2], c3 = spx[e + 3];
            int c4 = spx[e + 4], c5 = spx[e + 5], c6 = spx[e + 6], c7 = spx[e + 7];
            float v0 = spy[e],     v1 = spy[e + 1], v2 = spy[e + 2], v3 = spy[e + 3];
            float v4 = spy[e + 4], v5 = spy[e + 5], v6 = spy[e + 6], v7 = spy[e + 7];
            unsigned int s0 = *(const unsigned int*)(Sup + (size_t)c0 * AF + lane * 2);
            unsigned int s1 = *(const unsigned int*)(Sup + (size_t)c1 * AF + lane * 2);
            unsigned int s2 = *(const unsigned int*)(Sup + (size_t)c2 * AF + lane * 2);
            unsigned int s3 = *(const unsigned int*)(Sup + (size_t)c3 * AF + lane * 2);
            unsigned int s4 = *(const unsigned int*)(Sup + (size_t)c4 * AF + lane * 2);
            unsigned int s5 = *(const unsigned int*)(Sup + (size_t)c5 * AF + lane * 2);
            unsigned int s6 = *(const unsigned int*)(Sup + (size_t)c6 * AF + lane * 2);
            unsigned int s7 = *(const unsigned int*)(Sup + (size_t)c7 * AF + lane * 2);
            ax += v0 * bflo(s0) + v1 * bflo(s1) + v2 * bflo(s2) + v3 * bflo(s3)
                + v4 * bflo(s4) + v5 * bflo(s5) + v6 * bflo(s6) + v7 * bflo(s7);
            ay += v0 * bfhi(s0) + v1 * bfhi(s1) + v2 * bfhi(s2) + v3 * bfhi(s3)
                + v4 * bfhi(s4) + v5 * bfhi(s5) + v6 * bfhi(s6) + v7 * bfhi(s7);
        }
        for (; e < end; e++) {
            int c = spx[e];
            float vv = spy[e];
            unsigned int s = *(const unsigned int*)(Sup + (size_t)c * AF + lane * 2);
            ax += vv * bflo(s);
            ay += vv * bfhi(s);
        }
        out[(size_t)row * AF + lane]      = ax + b0;
        out[(size_t)row * AF + 64 + lane] = ay + b1;
    }
}

extern "C" void kernel_launch(void* const* d_in, const int* in_sizes, int n_in,
                              void* d_out, int out_size, void* d_ws, size_t ws_size,
                              hipStream_t stream) {
    const float* b_input   = (const float*)d_in[0];
    const int*   edge_rows = (const int*)d_in[1];
    const int*   edge_cols = (const int*)d_in[2];
    const float* edge_vals = (const float*)d_in[3];
    const float* a_weight  = (const float*)d_in[4];
    const float* a_bias    = (const float*)d_in[5];
    const int NB = in_sizes[0] / BF;
    const int NE = in_sizes[1];
    const int NA = out_size / AF;
    const int NBUCK = (NA + BROWS - 1) / BROWS;     // 1563 fine buckets
    const int NCOARSE = (NA + CROWS - 1) / CROWS;   // 98 coarse buckets
    float* out = (float*)d_out;

    // workspace layout (~60 MB)
    char* ws = (char*)d_ws;
    size_t off = 0;
    unsigned short* Sup = (unsigned short*)(ws + off); off += (size_t)NB * AF * sizeof(unsigned short);
    unsigned short* Wt  = (unsigned short*)(ws + off); off += (size_t)BF * AF * sizeof(unsigned short);
    int* grelC = (int*)(ws + off); off += 1024 * sizeof(int);
    int* grelF = (int*)(ws + off); off += 2048 * sizeof(int);
    int2* binnedC = (int2*)(ws + off); off += (size_t)NCOARSE * CAP_C * sizeof(int2);
    int2* binnedF = (int2*)(ws + off); off += (size_t)NBUCK * CAP_F * sizeof(int2);
    (void)ws_size; (void)n_in;

    hipMemsetAsync(grelC, 0, 3072 * sizeof(int), stream);   // grelC + grelF contiguous

    wtrans_kernel<<<64, 256, 0, stream>>>(a_weight, Wt);
    gemm_mfma_kernel<<<(NB + 63) / 64, 256, 0, stream>>>(b_input, Wt, Sup, NB);
    passA1_kernel<<<(NE + CHUNK1 - 1) / CHUNK1, 256, 0, stream>>>(
        edge_rows, edge_cols, edge_vals, grelC, binnedC, NE, NCOARSE);
    passA2_kernel<<<NCOARSE * 8, 256, 0, stream>>>(binnedC, grelC, grelF, binnedF, NBUCK);
    spmm_sorted_kernel<<<NBUCK, 512, 0, stream>>>(Sup, binnedF, grelF, a_bias, out, NA);
}

// Round 7
// 235.453 us; speedup vs baseline: 6.6759x; 1.0266x over previous
//
#include <hip/hip_runtime.h>
#include <hip/hip_bf16.h>

#define AF 128
#define BF 128
#define BROWS 64             // rows per fine bucket
#define CAP_F 1600           // slots per fine bucket (mean 1024, sigma 32)
#define CROWS 1024           // rows per coarse bucket (= 16 fine)
#define CAP_C 18432          // slots per coarse bucket (mean 16384, sigma 128)
#define CHUNK1 2048
#define NCOARSE_MAX 128

typedef __attribute__((ext_vector_type(8))) short bf16x8;
typedef __attribute__((ext_vector_type(4))) float f32x4;

__device__ inline unsigned short f2bf(float f) {
    unsigned int u = __float_as_uint(f);
    u += 0x7FFF + ((u >> 16) & 1);          // round-to-nearest-even
    return (unsigned short)(u >> 16);
}
__device__ inline unsigned int pk2bf(float x, float y) {
    __hip_bfloat162 h = __float22bfloat162_rn(make_float2(x, y));
    return *(unsigned int*)&h;
}
__device__ inline float bflo(unsigned int u) { return __uint_as_float(u << 16); }
__device__ inline float bfhi(unsigned int u) { return __uint_as_float(u & 0xFFFF0000u); }

// ---- one-time: Wt[n][k] = bf16(W[k][n]), 128x128 ----
__global__ void wtrans_kernel(const float* __restrict__ W, unsigned short* __restrict__ Wt) {
    int idx = blockIdx.x * 256 + threadIdx.x;   // grid 64 x 256
    int n = idx & 127, k = idx >> 7;
    Wt[n * 128 + k] = f2bf(W[(size_t)k * 128 + n]);
}

// ---- MFMA GEMM v2: A-frags direct from global (no As LDS, no 2nd barrier),
//      epilogue packs (nt, nt+4) pairs -> coalesced dword stores.
//      Sup layout interleaved: short index row*128 + 2*(f&63) + (f>>6).
__global__ __launch_bounds__(256) void gemm_mfma_kernel(const float* __restrict__ Bin,
                                                        const unsigned short* __restrict__ Wt,
                                                        unsigned int* __restrict__ Sup, int NB) {
    __shared__ unsigned short Ws[128][136];
    const int tid = threadIdx.x;
    const int lane = tid & 63;
    const int wave = tid >> 6;
    const int row0 = blockIdx.x * 64;
    const int m = lane & 15;
    const int quad = lane >> 4;

    {   // stage Wt (bf16): thread copies 128 B
        int r = tid >> 1;
        int c = (tid & 1) * 64;
        const uint4* src = (const uint4*)(Wt + r * 128 + c);
        uint4* dst = (uint4*)(&Ws[r][c]);
        #pragma unroll
        for (int i = 0; i < 8; i++) dst[i] = src[i];
    }

    // A fragments straight from global: lane reads row (row0+wave*16+m), k = ks*32+quad*8..+8
    int arow = row0 + wave * 16 + m;
    int arow_c = (arow < NB) ? arow : (NB - 1);       // clamp: garbage rows never stored
    const float* ap = Bin + (size_t)arow_c * BF + quad * 8;
    bf16x8 af[4];
    #pragma unroll
    for (int ks = 0; ks < 4; ks++) {
        float4 lo = *(const float4*)(ap + ks * 32);
        float4 hi = *(const float4*)(ap + ks * 32 + 4);
        union { unsigned int u[4]; bf16x8 v; } cv;
        cv.u[0] = pk2bf(lo.x, lo.y); cv.u[1] = pk2bf(lo.z, lo.w);
        cv.u[2] = pk2bf(hi.x, hi.y); cv.u[3] = pk2bf(hi.z, hi.w);
        af[ks] = cv.v;
    }
    __syncthreads();

    f32x4 acc[8];
    #pragma unroll
    for (int nt = 0; nt < 8; nt++) {
        f32x4 a = {0.f, 0.f, 0.f, 0.f};
        #pragma unroll
        for (int ks = 0; ks < 4; ks++) {
            bf16x8 bf = *(const bf16x8*)(&Ws[nt * 16 + m][ks * 32 + quad * 8]);
            a = __builtin_amdgcn_mfma_f32_16x16x32_bf16(af[ks], bf, a, 0, 0, 0);
        }
        acc[nt] = a;
    }
    // epilogue: f = nt*16+m (nt<4) pairs with f+64 = (nt+4)*16+m, same lane.
    // dword index = row*64 + f  -> lanes m 0..15 consecutive dwords (coalesced).
    #pragma unroll
    for (int nt = 0; nt < 4; nt++) {
        #pragma unroll
        for (int r = 0; r < 4; r++) {
            int row = row0 + wave * 16 + quad * 4 + r;
            if (row < NB)
                Sup[(size_t)row * 64 + nt * 16 + m] = pk2bf(acc[nt][r], acc[nt + 4][r]);
        }
    }
}

// ---- passA1: bin edges into 98 coarse regions; payload {col | lrow10<<17, val} ----
__global__ __launch_bounds__(256) void passA1_kernel(const int* __restrict__ rows,
                                                     const int* __restrict__ cols,
                                                     const float* __restrict__ vals,
                                                     int* __restrict__ grelC,
                                                     int2* __restrict__ binnedC, int NE, int NCOARSE) {
    __shared__ int h[NCOARSE_MAX];
    __shared__ int rbase[NCOARSE_MAX];
    int tid = threadIdx.x;
    if (tid < NCOARSE) h[tid] = 0;
    __syncthreads();
    int base = blockIdx.x * CHUNK1;
    #pragma unroll
    for (int i = 0; i < CHUNK1 / 256; i++) {
        int e = base + tid + i * 256;
        if (e < NE) atomicAdd(&h[rows[e] >> 10], 1);
    }
    __syncthreads();
    if (tid < NCOARSE) {
        int c = h[tid];
        rbase[tid] = tid * CAP_C + (c ? atomicAdd(&grelC[tid], c) : 0);
        h[tid] = 0;
    }
    __syncthreads();
    #pragma unroll
    for (int i = 0; i < CHUNK1 / 256; i++) {
        int e = base + tid + i * 256;
        if (e < NE) {
            int r = rows[e];
            int k = r >> 10;
            int lp = atomicAdd(&h[k], 1);
            int2 p;
            p.x = cols[e] | ((r & 1023) << 17);
            p.y = __float_as_int(vals[e]);
            binnedC[rbase[k] + lp] = p;
        }
    }
}

// ---- passA2: 8 blocks per coarse bucket -> scatter into 16 fine buckets each ----
__global__ __launch_bounds__(256) void passA2_kernel(const int2* __restrict__ binnedC,
                                                     const int* __restrict__ grelC,
                                                     int* __restrict__ grelF,
                                                     int2* __restrict__ binnedF, int NBUCK) {
    __shared__ int h[16];
    __shared__ int rb[16];
    const int tid = threadIdx.x;
    const int j = blockIdx.x >> 3;      // coarse bucket
    const int s = blockIdx.x & 7;       // slice
    int n = grelC[j]; if (n > CAP_C) n = CAP_C;
    const int st = (n * s) >> 3;
    const int en = (n * (s + 1)) >> 3;
    const int2* src = binnedC + (size_t)j * CAP_C;
    if (tid < 16) h[tid] = 0;
    __syncthreads();
    for (int i = st + tid; i < en; i += 256)
        atomicAdd(&h[src[i].x >> 23], 1);
    __syncthreads();
    if (tid < 16) {
        int c = h[tid];
        int fine = j * 16 + tid;
        rb[tid] = (fine < NBUCK) ? (fine * CAP_F + (c ? atomicAdd(&grelF[fine], c) : 0)) : 0;
        h[tid] = 0;
    }
    __syncthreads();
    for (int i = st + tid; i < en; i += 256) {
        int2 p = src[i];
        int sub = p.x >> 23;
        int lp = atomicAdd(&h[sub], 1);
        int2 q;
        q.x = p.x & 0x7FFFFF;           // col | lrow6<<17
        q.y = p.y;
        binnedF[(size_t)rb[sub] + lp] = q;
    }
}

// ---- fused per-bucket sort + atomic-free gather; 256 thr (8 blocks/CU), 64 rows ----
__global__ __launch_bounds__(256) void spmm_sorted_kernel(const unsigned short* __restrict__ Sup,
                                                          const int2* __restrict__ binned,
                                                          const int* __restrict__ grel,
                                                          const float* __restrict__ bias,
                                                          float* __restrict__ out, int NA) {
    __shared__ int   spx[CAP_F];
    __shared__ float spy[CAP_F];
    __shared__ int cnt[BROWS];
    __shared__ int sc[BROWS];
    __shared__ int rs[BROWS + 1];
    __shared__ int cur[BROWS];
    const int tid = threadIdx.x;
    const int b = blockIdx.x;
    int n = grel[b]; if (n > CAP_F) n = CAP_F;
    const int2* src = binned + (size_t)b * CAP_F;

    // single global read: stage this block's edges into registers (7*256 >= CAP_F)
    int2 pr[7];
    #pragma unroll
    for (int j = 0; j < 7; j++) {
        int i = tid + j * 256;
        pr[j] = (i < n) ? src[i] : make_int2(-1, 0);
    }
    if (tid < BROWS) cnt[tid] = 0;
    __syncthreads();
    #pragma unroll
    for (int j = 0; j < 7; j++)
        if (pr[j].x >= 0) atomicAdd(&cnt[(pr[j].x >> 17) & 63], 1);
    __syncthreads();
    int v = (tid < BROWS) ? cnt[tid] : 0;
    int x = v;
    if (tid < BROWS) sc[tid] = x;
    __syncthreads();
    #pragma unroll
    for (int off = 1; off < BROWS; off <<= 1) {
        int t = (tid < BROWS && tid >= off) ? sc[tid - off] : 0;
        __syncthreads();
        if (tid < BROWS) { x += t; sc[tid] = x; }
        __syncthreads();
    }
    if (tid < BROWS) { rs[tid] = x - v; cur[tid] = x - v; }
    if (tid == BROWS - 1) rs[BROWS] = x;
    __syncthreads();
    #pragma unroll
    for (int j = 0; j < 7; j++) {
        if (pr[j].x >= 0) {
            int lr = (pr[j].x >> 17) & 63;
            int pos = atomicAdd(&cur[lr], 1);
            spx[pos] = pr[j].x & 0x1FFFF;
            spy[pos] = __int_as_float(pr[j].y);
        }
    }
    __syncthreads();

    const int lane = tid & 63;
    const int wv = tid >> 6;
    const float b0 = bias[lane];
    const float b1 = bias[64 + lane];
    for (int lr = wv; lr < BROWS; lr += 4) {
        int row = b * BROWS + lr;
        if (row >= NA) break;
        int e = rs[lr], end = rs[lr + 1];
        float ax = 0.f, ay = 0.f;
        for (; e + 8 <= end; e += 8) {
            int c0 = spx[e],     c1 = spx[e + 1], c2 = spx[e + 2], c3 = spx[e + 3];
            int c4 = spx[e + 4], c5 = spx[e + 5], c6 = spx[e + 6], c7 = spx[e + 7];
            float v0 = spy[e],     v1 = spy[e + 1], v2 = spy[e + 2], v3 = spy[e + 3];
            float v4 = spy[e + 4], v5 = spy[e + 5], v6 = spy[e + 6], v7 = spy[e + 7];
            unsigned int s0 = *(const unsigned int*)(Sup + (size_t)c0 * AF + lane * 2);
            unsigned int s1 = *(const unsigned int*)(Sup + (size_t)c1 * AF + lane * 2);
            unsigned int s2 = *(const unsigned int*)(Sup + (size_t)c2 * AF + lane * 2);
            unsigned int s3 = *(const unsigned int*)(Sup + (size_t)c3 * AF + lane * 2);
            unsigned int s4 = *(const unsigned int*)(Sup + (size_t)c4 * AF + lane * 2);
            unsigned int s5 = *(const unsigned int*)(Sup + (size_t)c5 * AF + lane * 2);
            unsigned int s6 = *(const unsigned int*)(Sup + (size_t)c6 * AF + lane * 2);
            unsigned int s7 = *(const unsigned int*)(Sup + (size_t)c7 * AF + lane * 2);
            ax += v0 * bflo(s0) + v1 * bflo(s1) + v2 * bflo(s2) + v3 * bflo(s3)
                + v4 * bflo(s4) + v5 * bflo(s5) + v6 * bflo(s6) + v7 * bflo(s7);
            ay += v0 * bfhi(s0) + v1 * bfhi(s1) + v2 * bfhi(s2) + v3 * bfhi(s3)
                + v4 * bfhi(s4) + v5 * bfhi(s5) + v6 * bfhi(s6) + v7 * bfhi(s7);
        }
        for (; e < end; e++) {
            int c = spx[e];
            float vv = spy[e];
            unsigned int s = *(const unsigned int*)(Sup + (size_t)c * AF + lane * 2);
            ax += vv * bflo(s);
            ay += vv * bfhi(s);
        }
        out[(size_t)row * AF + lane]      = ax + b0;
        out[(size_t)row * AF + 64 + lane] = ay + b1;
    }
}

extern "C" void kernel_launch(void* const* d_in, const int* in_sizes, int n_in,
                              void* d_out, int out_size, void* d_ws, size_t ws_size,
                              hipStream_t stream) {
    const float* b_input   = (const float*)d_in[0];
    const int*   edge_rows = (const int*)d_in[1];
    const int*   edge_cols = (const int*)d_in[2];
    const float* edge_vals = (const float*)d_in[3];
    const float* a_weight  = (const float*)d_in[4];
    const float* a_bias    = (const float*)d_in[5];
    const int NB = in_sizes[0] / BF;
    const int NE = in_sizes[1];
    const int NA = out_size / AF;
    const int NBUCK = (NA + BROWS - 1) / BROWS;     // 1563 fine buckets
    const int NCOARSE = (NA + CROWS - 1) / CROWS;   // 98 coarse buckets
    float* out = (float*)d_out;

    // workspace layout (~60 MB)
    char* ws = (char*)d_ws;
    size_t off = 0;
    unsigned short* Sup = (unsigned short*)(ws + off); off += (size_t)NB * AF * sizeof(unsigned short);
    unsigned short* Wt  = (unsigned short*)(ws + off); off += (size_t)BF * AF * sizeof(unsigned short);
    int* grelC = (int*)(ws + off); off += 1024 * sizeof(int);
    int* grelF = (int*)(ws + off); off += 2048 * sizeof(int);
    int2* binnedC = (int2*)(ws + off); off += (size_t)NCOARSE * CAP_C * sizeof(int2);
    int2* binnedF = (int2*)(ws + off); off += (size_t)NBUCK * CAP_F * sizeof(int2);
    (void)ws_size; (void)n_in;

    hipMemsetAsync(grelC, 0, 3072 * sizeof(int), stream);   // grelC + grelF contiguous

    wtrans_kernel<<<64, 256, 0, stream>>>(a_weight, Wt);
    gemm_mfma_kernel<<<(NB + 63) / 64, 256, 0, stream>>>(b_input, Wt, (unsigned int*)Sup, NB);
    passA1_kernel<<<(NE + CHUNK1 - 1) / CHUNK1, 256, 0, stream>>>(
        edge_rows, edge_cols, edge_vals, grelC, binnedC, NE, NCOARSE);
    passA2_kernel<<<NCOARSE * 8, 256, 0, stream>>>(binnedC, grelC, grelF, binnedF, NBUCK);
    spmm_sorted_kernel<<<NBUCK, 256, 0, stream>>>(Sup, binnedF, grelF, a_bias, out, NA);
}

// Round 8
// 233.000 us; speedup vs baseline: 6.7462x; 1.0105x over previous
//
#include <hip/hip_runtime.h>
#include <hip/hip_bf16.h>

#define AF 128
#define BF 128
#define BROWS 64             // rows per fine bucket
#define CAP_F 1600           // slots per fine bucket (mean 1024, sigma 32)
#define SORT_CAP 1664        // CAP_F + row-padding slack (<= 64*7 = 448; max n ~1160)
#define CROWS 1024           // rows per coarse bucket (= 16 fine)
#define CAP_C 18432          // slots per coarse bucket (mean 16384, sigma 128)
#define CHUNK1 2048
#define NCOARSE_MAX 128

typedef __attribute__((ext_vector_type(8))) short bf16x8;
typedef __attribute__((ext_vector_type(4))) float f32x4;

__device__ inline unsigned short f2bf(float f) {
    unsigned int u = __float_as_uint(f);
    u += 0x7FFF + ((u >> 16) & 1);          // round-to-nearest-even
    return (unsigned short)(u >> 16);
}
__device__ inline unsigned int pk2bf(float x, float y) {
    __hip_bfloat162 h = __float22bfloat162_rn(make_float2(x, y));
    return *(unsigned int*)&h;
}
__device__ inline float bflo(unsigned int u) { return __uint_as_float(u << 16); }
__device__ inline float bfhi(unsigned int u) { return __uint_as_float(u & 0xFFFF0000u); }

// ---- phase1: blocks [0, ngemm) = MFMA GEMM (W transposed in-staging);
//              blocks [ngemm, ...) = passA1 coarse binning. Independent work,
//              co-scheduled in one dispatch (MFMA blocks overlap LD/atomic blocks).
__global__ __launch_bounds__(256) void phase1_kernel(const float* __restrict__ Bin,
                                                     const float* __restrict__ W,
                                                     unsigned int* __restrict__ Sup, int NB,
                                                     const int* __restrict__ rows,
                                                     const int* __restrict__ cols,
                                                     const float* __restrict__ vals,
                                                     int* __restrict__ grelC,
                                                     int2* __restrict__ binnedC,
                                                     int NE, int NCOARSE, int ngemm) {
    __shared__ unsigned short Ws[128][136];
    __shared__ int h[NCOARSE_MAX];
    __shared__ int rbase[NCOARSE_MAX];
    const int tid = threadIdx.x;

    if ((int)blockIdx.x < ngemm) {
        // ---------------- GEMM part ----------------
        const int lane = tid & 63;
        const int wave = tid >> 6;
        const int row0 = blockIdx.x * 64;
        const int m = lane & 15;
        const int quad = lane >> 4;

        {   // stage W transposed: Ws[n][k] = bf16(W[k][n]); thread reads 64 floats of row k
            int k = tid >> 1;
            int n0 = (tid & 1) * 64;
            const float4* src = (const float4*)(W + (size_t)k * AF + n0);
            #pragma unroll
            for (int i = 0; i < 16; i++) {
                float4 v = src[i];
                int n = n0 + i * 4;
                Ws[n + 0][k] = f2bf(v.x);
                Ws[n + 1][k] = f2bf(v.y);
                Ws[n + 2][k] = f2bf(v.z);
                Ws[n + 3][k] = f2bf(v.w);
            }
        }
        // A fragments straight from global
        int arow = row0 + wave * 16 + m;
        int arow_c = (arow < NB) ? arow : (NB - 1);
        const float* ap = Bin + (size_t)arow_c * BF + quad * 8;
        bf16x8 af[4];
        #pragma unroll
        for (int ks = 0; ks < 4; ks++) {
            float4 lo = *(const float4*)(ap + ks * 32);
            float4 hi = *(const float4*)(ap + ks * 32 + 4);
            union { unsigned int u[4]; bf16x8 v; } cv;
            cv.u[0] = pk2bf(lo.x, lo.y); cv.u[1] = pk2bf(lo.z, lo.w);
            cv.u[2] = pk2bf(hi.x, hi.y); cv.u[3] = pk2bf(hi.z, hi.w);
            af[ks] = cv.v;
        }
        __syncthreads();

        f32x4 acc[8];
        #pragma unroll
        for (int nt = 0; nt < 8; nt++) {
            f32x4 a = {0.f, 0.f, 0.f, 0.f};
            #pragma unroll
            for (int ks = 0; ks < 4; ks++) {
                bf16x8 bf = *(const bf16x8*)(&Ws[nt * 16 + m][ks * 32 + quad * 8]);
                a = __builtin_amdgcn_mfma_f32_16x16x32_bf16(af[ks], bf, a, 0, 0, 0);
            }
            acc[nt] = a;
        }
        // packed epilogue: dword = row*64 + nt*16+m holds feats (f, f+64)
        #pragma unroll
        for (int nt = 0; nt < 4; nt++) {
            #pragma unroll
            for (int r = 0; r < 4; r++) {
                int row = row0 + wave * 16 + quad * 4 + r;
                if (row < NB)
                    Sup[(size_t)row * 64 + nt * 16 + m] = pk2bf(acc[nt][r], acc[nt + 4][r]);
            }
        }
    } else {
        // ---------------- passA1 part ----------------
        int bid = blockIdx.x - ngemm;
        if (tid < NCOARSE) h[tid] = 0;
        __syncthreads();
        int base = bid * CHUNK1;
        #pragma unroll
        for (int i = 0; i < CHUNK1 / 256; i++) {
            int e = base + tid + i * 256;
            if (e < NE) atomicAdd(&h[rows[e] >> 10], 1);
        }
        __syncthreads();
        if (tid < NCOARSE) {
            int c = h[tid];
            rbase[tid] = tid * CAP_C + (c ? atomicAdd(&grelC[tid], c) : 0);
            h[tid] = 0;
        }
        __syncthreads();
        #pragma unroll
        for (int i = 0; i < CHUNK1 / 256; i++) {
            int e = base + tid + i * 256;
            if (e < NE) {
                int r = rows[e];
                int k = r >> 10;
                int lp = atomicAdd(&h[k], 1);
                int2 p;
                p.x = cols[e] | ((r & 1023) << 17);
                p.y = __float_as_int(vals[e]);
                binnedC[rbase[k] + lp] = p;
            }
        }
    }
}

// ---- passA2: 8 blocks per coarse bucket -> scatter into 16 fine buckets each ----
__global__ __launch_bounds__(256) void passA2_kernel(const int2* __restrict__ binnedC,
                                                     const int* __restrict__ grelC,
                                                     int* __restrict__ grelF,
                                                     int2* __restrict__ binnedF, int NBUCK) {
    __shared__ int h[16];
    __shared__ int rb[16];
    const int tid = threadIdx.x;
    const int j = blockIdx.x >> 3;      // coarse bucket
    const int s = blockIdx.x & 7;       // slice
    int n = grelC[j]; if (n > CAP_C) n = CAP_C;
    const int st = (n * s) >> 3;
    const int en = (n * (s + 1)) >> 3;
    const int2* src = binnedC + (size_t)j * CAP_C;
    if (tid < 16) h[tid] = 0;
    __syncthreads();
    for (int i = st + tid; i < en; i += 256)
        atomicAdd(&h[src[i].x >> 23], 1);
    __syncthreads();
    if (tid < 16) {
        int c = h[tid];
        int fine = j * 16 + tid;
        rb[tid] = (fine < NBUCK) ? (fine * CAP_F + (c ? atomicAdd(&grelF[fine], c) : 0)) : 0;
        h[tid] = 0;
    }
    __syncthreads();
    for (int i = st + tid; i < en; i += 256) {
        int2 p = src[i];
        int sub = p.x >> 23;
        int lp = atomicAdd(&h[sub], 1);
        int2 q;
        q.x = p.x & 0x7FFFFF;           // col | lrow6<<17
        q.y = p.y;
        binnedF[(size_t)rb[sub] + lp] = q;
    }
}

// ---- fused per-bucket sort + atomic-free gather; rows padded to x8 -> no tails ----
__global__ __launch_bounds__(256) void spmm_sorted_kernel(const unsigned short* __restrict__ Sup,
                                                          const int2* __restrict__ binned,
                                                          const int* __restrict__ grel,
                                                          const float* __restrict__ bias,
                                                          float* __restrict__ out, int NA) {
    __shared__ int2 spxy[SORT_CAP];     // sorted {col, val} (13.3 KB)
    __shared__ int cnt[BROWS];
    __shared__ int sc[BROWS];
    __shared__ int rs[BROWS + 1];
    __shared__ int cur[BROWS];
    const int tid = threadIdx.x;
    const int b = blockIdx.x;
    int n = grel[b]; if (n > CAP_F) n = CAP_F;
    const int2* src = binned + (size_t)b * CAP_F;

    // single global read: stage this block's edges into registers (7*256 >= CAP_F)
    int2 pr[7];
    #pragma unroll
    for (int j = 0; j < 7; j++) {
        int i = tid + j * 256;
        pr[j] = (i < n) ? src[i] : make_int2(-1, 0);
    }
    if (tid < BROWS) cnt[tid] = 0;
    __syncthreads();
    #pragma unroll
    for (int j = 0; j < 7; j++)
        if (pr[j].x >= 0) atomicAdd(&cnt[(pr[j].x >> 17) & 63], 1);
    __syncthreads();
    // scan of counts padded to multiple of 8 (dummy slots keep gather tail-free)
    int v = (tid < BROWS) ? ((cnt[tid] + 7) & ~7) : 0;
    int x = v;
    if (tid < BROWS) sc[tid] = x;
    __syncthreads();
    #pragma unroll
    for (int off = 1; off < BROWS; off <<= 1) {
        int t = (tid < BROWS && tid >= off) ? sc[tid - off] : 0;
        __syncthreads();
        if (tid < BROWS) { x += t; sc[tid] = x; }
        __syncthreads();
    }
    if (tid < BROWS) { rs[tid] = x - v; cur[tid] = x - v; }
    if (tid == BROWS - 1) rs[BROWS] = x;
    __syncthreads();
    #pragma unroll
    for (int j = 0; j < 7; j++) {
        if (pr[j].x >= 0) {
            int lr = (pr[j].x >> 17) & 63;
            int pos = atomicAdd(&cur[lr], 1);
            spxy[pos] = make_int2(pr[j].x & 0x1FFFF, pr[j].y);
        }
    }
    __syncthreads();
    // fill pad slots: col 0 * val 0.0 contributes nothing
    if (tid < BROWS) {
        int end = rs[tid + 1];
        for (int p = cur[tid]; p < end; p++) spxy[p] = make_int2(0, 0);
    }
    __syncthreads();

    const int lane = tid & 63;
    const int wv = tid >> 6;
    const float b0 = bias[lane];
    const float b1 = bias[64 + lane];
    for (int lr = wv; lr < BROWS; lr += 4) {
        int row = b * BROWS + lr;
        if (row >= NA) break;
        int e = rs[lr], end = rs[lr + 1];
        float ax = 0.f, ay = 0.f;
        for (; e < end; e += 8) {       // exact multiples of 8, no tail
            int2 q0 = spxy[e],     q1 = spxy[e + 1], q2 = spxy[e + 2], q3 = spxy[e + 3];
            int2 q4 = spxy[e + 4], q5 = spxy[e + 5], q6 = spxy[e + 6], q7 = spxy[e + 7];
            unsigned int s0 = *(const unsigned int*)(Sup + (size_t)q0.x * AF + lane * 2);
            unsigned int s1 = *(const unsigned int*)(Sup + (size_t)q1.x * AF + lane * 2);
            unsigned int s2 = *(const unsigned int*)(Sup + (size_t)q2.x * AF + lane * 2);
            unsigned int s3 = *(const unsigned int*)(Sup + (size_t)q3.x * AF + lane * 2);
            unsigned int s4 = *(const unsigned int*)(Sup + (size_t)q4.x * AF + lane * 2);
            unsigned int s5 = *(const unsigned int*)(Sup + (size_t)q5.x * AF + lane * 2);
            unsigned int s6 = *(const unsigned int*)(Sup + (size_t)q6.x * AF + lane * 2);
            unsigned int s7 = *(const unsigned int*)(Sup + (size_t)q7.x * AF + lane * 2);
            float v0 = __int_as_float(q0.y), v1 = __int_as_float(q1.y);
            float v2 = __int_as_float(q2.y), v3 = __int_as_float(q3.y);
            float v4 = __int_as_float(q4.y), v5 = __int_as_float(q5.y);
            float v6 = __int_as_float(q6.y), v7 = __int_as_float(q7.y);
            ax += v0 * bflo(s0) + v1 * bflo(s1) + v2 * bflo(s2) + v3 * bflo(s3)
                + v4 * bflo(s4) + v5 * bflo(s5) + v6 * bflo(s6) + v7 * bflo(s7);
            ay += v0 * bfhi(s0) + v1 * bfhi(s1) + v2 * bfhi(s2) + v3 * bfhi(s3)
                + v4 * bfhi(s4) + v5 * bfhi(s5) + v6 * bfhi(s6) + v7 * bfhi(s7);
        }
        out[(size_t)row * AF + lane]      = ax + b0;
        out[(size_t)row * AF + 64 + lane] = ay + b1;
    }
}

extern "C" void kernel_launch(void* const* d_in, const int* in_sizes, int n_in,
                              void* d_out, int out_size, void* d_ws, size_t ws_size,
                              hipStream_t stream) {
    const float* b_input   = (const float*)d_in[0];
    const int*   edge_rows = (const int*)d_in[1];
    const int*   edge_cols = (const int*)d_in[2];
    const float* edge_vals = (const float*)d_in[3];
    const float* a_weight  = (const float*)d_in[4];
    const float* a_bias    = (const float*)d_in[5];
    const int NB = in_sizes[0] / BF;
    const int NE = in_sizes[1];
    const int NA = out_size / AF;
    const int NBUCK = (NA + BROWS - 1) / BROWS;     // 1563 fine buckets
    const int NCOARSE = (NA + CROWS - 1) / CROWS;   // 98 coarse buckets
    float* out = (float*)d_out;

    // workspace layout (~60 MB)
    char* ws = (char*)d_ws;
    size_t off = 0;
    unsigned short* Sup = (unsigned short*)(ws + off); off += (size_t)NB * AF * sizeof(unsigned short);
    int* grelC = (int*)(ws + off); off += 1024 * sizeof(int);
    int* grelF = (int*)(ws + off); off += 2048 * sizeof(int);
    int2* binnedC = (int2*)(ws + off); off += (size_t)NCOARSE * CAP_C * sizeof(int2);
    int2* binnedF = (int2*)(ws + off); off += (size_t)NBUCK * CAP_F * sizeof(int2);
    (void)ws_size; (void)n_in;

    hipMemsetAsync(grelC, 0, 3072 * sizeof(int), stream);   // grelC + grelF contiguous

    const int ngemm = (NB + 63) / 64;                 // 1563
    const int npass = (NE + CHUNK1 - 1) / CHUNK1;     // 782
    phase1_kernel<<<ngemm + npass, 256, 0, stream>>>(
        b_input, a_weight, (unsigned int*)Sup, NB,
        edge_rows, edge_cols, edge_vals, grelC, binnedC, NE, NCOARSE, ngemm);
    passA2_kernel<<<NCOARSE * 8, 256, 0, stream>>>(binnedC, grelC, grelF, binnedF, NBUCK);
    spmm_sorted_kernel<<<NBUCK, 256, 0, stream>>>(Sup, binnedF, grelF, a_bias, out, NA);
}

// Round 9
// 221.677 us; speedup vs baseline: 7.0908x; 1.0511x over previous
//
#include <hip/hip_runtime.h>
#include <hip/hip_bf16.h>

#define AF 128
#define BF 128
#define BROWS 64             // rows per fine bucket
#define CAP_F 1600           // slots per fine bucket (mean 1024, sigma 32)
#define SORT_CAP 1664        // CAP_F + row-padding slack
#define CROWS 1024           // rows per coarse bucket (= 16 fine)
#define CAP_C 18432          // slots per coarse bucket (mean 16384, sigma 128)
#define CHUNK1 2048
#define NCOARSE_MAX 128

typedef __attribute__((ext_vector_type(8))) short bf16x8;
typedef __attribute__((ext_vector_type(4))) float f32x4;

__device__ inline unsigned short f2bf(float f) {
    unsigned int u = __float_as_uint(f);
    u += 0x7FFF + ((u >> 16) & 1);          // round-to-nearest-even
    return (unsigned short)(u >> 16);
}
__device__ inline unsigned int pk2bf(float x, float y) {
    __hip_bfloat162 h = __float22bfloat162_rn(make_float2(x, y));
    return *(unsigned int*)&h;
}
__device__ inline float bflo(unsigned int u) { return __uint_as_float(u << 16); }
__device__ inline float bfhi(unsigned int u) { return __uint_as_float(u & 0xFFFF0000u); }

// ---- phase1: blocks [0, ngemm) = MFMA GEMM; blocks [ngemm,...) = passA1 ----
__global__ __launch_bounds__(256) void phase1_kernel(const float* __restrict__ Bin,
                                                     const float* __restrict__ W,
                                                     unsigned int* __restrict__ Sup, int NB,
                                                     const int* __restrict__ rows,
                                                     const int* __restrict__ cols,
                                                     const float* __restrict__ vals,
                                                     int* __restrict__ grelC,
                                                     int2* __restrict__ binnedC,
                                                     int NE, int NCOARSE, int ngemm) {
    __shared__ unsigned short Ws[128][136];
    __shared__ int h[NCOARSE_MAX];
    __shared__ int rbase[NCOARSE_MAX];
    const int tid = threadIdx.x;

    if ((int)blockIdx.x < ngemm) {
        // ---------------- GEMM part ----------------
        const int lane = tid & 63;
        const int wave = tid >> 6;
        const int row0 = blockIdx.x * 64;
        const int m = lane & 15;
        const int quad = lane >> 4;

        {   // stage W transposed: Ws[n][k] = bf16(W[k][n])
            int k = tid >> 1;
            int n0 = (tid & 1) * 64;
            const float4* src = (const float4*)(W + (size_t)k * AF + n0);
            #pragma unroll
            for (int i = 0; i < 16; i++) {
                float4 v = src[i];
                int n = n0 + i * 4;
                Ws[n + 0][k] = f2bf(v.x);
                Ws[n + 1][k] = f2bf(v.y);
                Ws[n + 2][k] = f2bf(v.z);
                Ws[n + 3][k] = f2bf(v.w);
            }
        }
        int arow = row0 + wave * 16 + m;
        int arow_c = (arow < NB) ? arow : (NB - 1);
        const float* ap = Bin + (size_t)arow_c * BF + quad * 8;
        bf16x8 af[4];
        #pragma unroll
        for (int ks = 0; ks < 4; ks++) {
            float4 lo = *(const float4*)(ap + ks * 32);
            float4 hi = *(const float4*)(ap + ks * 32 + 4);
            union { unsigned int u[4]; bf16x8 v; } cv;
            cv.u[0] = pk2bf(lo.x, lo.y); cv.u[1] = pk2bf(lo.z, lo.w);
            cv.u[2] = pk2bf(hi.x, hi.y); cv.u[3] = pk2bf(hi.z, hi.w);
            af[ks] = cv.v;
        }
        __syncthreads();

        f32x4 acc[8];
        #pragma unroll
        for (int nt = 0; nt < 8; nt++) {
            f32x4 a = {0.f, 0.f, 0.f, 0.f};
            #pragma unroll
            for (int ks = 0; ks < 4; ks++) {
                bf16x8 bf = *(const bf16x8*)(&Ws[nt * 16 + m][ks * 32 + quad * 8]);
                a = __builtin_amdgcn_mfma_f32_16x16x32_bf16(af[ks], bf, a, 0, 0, 0);
            }
            acc[nt] = a;
        }
        #pragma unroll
        for (int nt = 0; nt < 4; nt++) {
            #pragma unroll
            for (int r = 0; r < 4; r++) {
                int row = row0 + wave * 16 + quad * 4 + r;
                if (row < NB)
                    Sup[(size_t)row * 64 + nt * 16 + m] = pk2bf(acc[nt][r], acc[nt + 4][r]);
            }
        }
    } else {
        // ---------------- passA1 part: single global pass, register-staged ----------------
        int bid = blockIdx.x - ngemm;
        int base = bid * CHUNK1;
        int ke[8]; int px[8]; float pv[8];
        #pragma unroll
        for (int i = 0; i < 8; i++) {
            int e = base + tid + i * 256;
            if (e < NE) {
                int r = rows[e];
                ke[i] = r >> 10;
                px[i] = cols[e] | ((r & 1023) << 17);
                pv[i] = vals[e];
            } else ke[i] = -1;
        }
        if (tid < NCOARSE) h[tid] = 0;
        __syncthreads();
        #pragma unroll
        for (int i = 0; i < 8; i++)
            if (ke[i] >= 0) atomicAdd(&h[ke[i]], 1);
        __syncthreads();
        if (tid < NCOARSE) {
            int c = h[tid];
            rbase[tid] = tid * CAP_C + (c ? atomicAdd(&grelC[tid], c) : 0);
            h[tid] = 0;
        }
        __syncthreads();
        #pragma unroll
        for (int i = 0; i < 8; i++) {
            if (ke[i] >= 0) {
                int lp = atomicAdd(&h[ke[i]], 1);
                binnedC[rbase[ke[i]] + lp] = make_int2(px[i], __float_as_int(pv[i]));
            }
        }
    }
}

// ---- passA2: 16 slices per coarse bucket (1568 blocks), register-staged single pass ----
__global__ __launch_bounds__(256) void passA2_kernel(const int2* __restrict__ binnedC,
                                                     const int* __restrict__ grelC,
                                                     int* __restrict__ grelF,
                                                     int2* __restrict__ binnedF, int NBUCK) {
    __shared__ int h[16];
    __shared__ int rb[16];
    const int tid = threadIdx.x;
    const int j = blockIdx.x >> 4;      // coarse bucket
    const int s = blockIdx.x & 15;      // slice
    int n = grelC[j]; if (n > CAP_C) n = CAP_C;
    const int st = (n * s) >> 4;
    const int en = (n * (s + 1)) >> 4;  // slice <= 1152 <= 5*256
    const int2* src = binnedC + (size_t)j * CAP_C;

    int sub[5]; int qx[5]; int qy[5];
    #pragma unroll
    for (int i = 0; i < 5; i++) {
        int idx = st + tid + i * 256;
        if (idx < en) {
            int2 p = src[idx];
            sub[i] = p.x >> 23;
            qx[i] = p.x & 0x7FFFFF;
            qy[i] = p.y;
        } else sub[i] = -1;
    }
    if (tid < 16) h[tid] = 0;
    __syncthreads();
    #pragma unroll
    for (int i = 0; i < 5; i++)
        if (sub[i] >= 0) atomicAdd(&h[sub[i]], 1);
    __syncthreads();
    if (tid < 16) {
        int c = h[tid];
        int fine = j * 16 + tid;
        rb[tid] = (fine < NBUCK) ? (fine * CAP_F + (c ? atomicAdd(&grelF[fine], c) : 0)) : 0;
        h[tid] = 0;
    }
    __syncthreads();
    #pragma unroll
    for (int i = 0; i < 5; i++) {
        if (sub[i] >= 0) {
            int lp = atomicAdd(&h[sub[i]], 1);
            binnedF[(size_t)rb[sub[i]] + lp] = make_int2(qx[i], qy[i]);
        }
    }
}

// ---- fused per-bucket sort + atomic-free gather; rows padded to x8 -> no tails ----
__global__ __launch_bounds__(256) void spmm_sorted_kernel(const unsigned short* __restrict__ Sup,
                                                          const int2* __restrict__ binned,
                                                          const int* __restrict__ grel,
                                                          const float* __restrict__ bias,
                                                          float* __restrict__ out, int NA) {
    __shared__ int2 spxy[SORT_CAP];
    __shared__ int cnt[BROWS];
    __shared__ int rs[BROWS + 1];
    __shared__ int cur[BROWS];
    const int tid = threadIdx.x;
    const int b = blockIdx.x;
    int n = grel[b]; if (n > CAP_F) n = CAP_F;
    const int2* src = binned + (size_t)b * CAP_F;

    int2 pr[7];
    #pragma unroll
    for (int j = 0; j < 7; j++) {
        int i = tid + j * 256;
        pr[j] = (i < n) ? src[i] : make_int2(-1, 0);
    }
    if (tid < BROWS) cnt[tid] = 0;
    __syncthreads();
    #pragma unroll
    for (int j = 0; j < 7; j++)
        if (pr[j].x >= 0) atomicAdd(&cnt[(pr[j].x >> 17) & 63], 1);
    __syncthreads();
    // wave-0 shfl scan over 64 counters (padded to x8), single barrier
    if (tid < 64) {
        int v = (cnt[tid] + 7) & ~7;
        int x = v;
        #pragma unroll
        for (int off = 1; off < 64; off <<= 1) {
            int t = __shfl_up(x, off);
            if (tid >= off) x += t;
        }
        rs[tid] = x - v;
        cur[tid] = x - v;
        if (tid == 63) rs[64] = x;
    }
    __syncthreads();
    #pragma unroll
    for (int j = 0; j < 7; j++) {
        if (pr[j].x >= 0) {
            int lr = (pr[j].x >> 17) & 63;
            int pos = atomicAdd(&cur[lr], 1);
            spxy[pos] = make_int2(pr[j].x & 0x1FFFF, pr[j].y);
        }
    }
    __syncthreads();
    if (tid < BROWS) {      // pad slots: col 0, val 0 contribute nothing
        int end = rs[tid + 1];
        for (int p = cur[tid]; p < end; p++) spxy[p] = make_int2(0, 0);
    }
    __syncthreads();

    const int lane = tid & 63;
    const int wv = tid >> 6;
    const float b0 = bias[lane];
    const float b1 = bias[64 + lane];
    for (int lr = wv; lr < BROWS; lr += 4) {
        int row = b * BROWS + lr;
        if (row >= NA) break;
        int e = rs[lr], end = rs[lr + 1];
        float ax = 0.f, ay = 0.f;
        for (; e < end; e += 8) {
            int2 q0 = spxy[e],     q1 = spxy[e + 1], q2 = spxy[e + 2], q3 = spxy[e + 3];
            int2 q4 = spxy[e + 4], q5 = spxy[e + 5], q6 = spxy[e + 6], q7 = spxy[e + 7];
            unsigned int s0 = *(const unsigned int*)(Sup + (size_t)q0.x * AF + lane * 2);
            unsigned int s1 = *(const unsigned int*)(Sup + (size_t)q1.x * AF + lane * 2);
            unsigned int s2 = *(const unsigned int*)(Sup + (size_t)q2.x * AF + lane * 2);
            unsigned int s3 = *(const unsigned int*)(Sup + (size_t)q3.x * AF + lane * 2);
            unsigned int s4 = *(const unsigned int*)(Sup + (size_t)q4.x * AF + lane * 2);
            unsigned int s5 = *(const unsigned int*)(Sup + (size_t)q5.x * AF + lane * 2);
            unsigned int s6 = *(const unsigned int*)(Sup + (size_t)q6.x * AF + lane * 2);
            unsigned int s7 = *(const unsigned int*)(Sup + (size_t)q7.x * AF + lane * 2);
            float v0 = __int_as_float(q0.y), v1 = __int_as_float(q1.y);
            float v2 = __int_as_float(q2.y), v3 = __int_as_float(q3.y);
            float v4 = __int_as_float(q4.y), v5 = __int_as_float(q5.y);
            float v6 = __int_as_float(q6.y), v7 = __int_as_float(q7.y);
            ax += v0 * bflo(s0) + v1 * bflo(s1) + v2 * bflo(s2) + v3 * bflo(s3)
                + v4 * bflo(s4) + v5 * bflo(s5) + v6 * bflo(s6) + v7 * bflo(s7);
            ay += v0 * bfhi(s0) + v1 * bfhi(s1) + v2 * bfhi(s2) + v3 * bfhi(s3)
                + v4 * bfhi(s4) + v5 * bfhi(s5) + v6 * bfhi(s6) + v7 * bfhi(s7);
        }
        out[(size_t)row * AF + lane]      = ax + b0;
        out[(size_t)row * AF + 64 + lane] = ay + b1;
    }
}

extern "C" void kernel_launch(void* const* d_in, const int* in_sizes, int n_in,
                              void* d_out, int out_size, void* d_ws, size_t ws_size,
                              hipStream_t stream) {
    const float* b_input   = (const float*)d_in[0];
    const int*   edge_rows = (const int*)d_in[1];
    const int*   edge_cols = (const int*)d_in[2];
    const float* edge_vals = (const float*)d_in[3];
    const float* a_weight  = (const float*)d_in[4];
    const float* a_bias    = (const float*)d_in[5];
    const int NB = in_sizes[0] / BF;
    const int NE = in_sizes[1];
    const int NA = out_size / AF;
    const int NBUCK = (NA + BROWS - 1) / BROWS;     // 1563 fine buckets
    const int NCOARSE = (NA + CROWS - 1) / CROWS;   // 98 coarse buckets
    float* out = (float*)d_out;

    char* ws = (char*)d_ws;
    size_t off = 0;
    unsigned short* Sup = (unsigned short*)(ws + off); off += (size_t)NB * AF * sizeof(unsigned short);
    int* grelC = (int*)(ws + off); off += 1024 * sizeof(int);
    int* grelF = (int*)(ws + off); off += 2048 * sizeof(int);
    int2* binnedC = (int2*)(ws + off); off += (size_t)NCOARSE * CAP_C * sizeof(int2);
    int2* binnedF = (int2*)(ws + off); off += (size_t)NBUCK * CAP_F * sizeof(int2);
    (void)ws_size; (void)n_in;

    hipMemsetAsync(grelC, 0, 3072 * sizeof(int), stream);

    const int ngemm = (NB + 63) / 64;                 // 1563
    const int npass = (NE + CHUNK1 - 1) / CHUNK1;     // 782
    phase1_kernel<<<ngemm + npass, 256, 0, stream>>>(
        b_input, a_weight, (unsigned int*)Sup, NB,
        edge_rows, edge_cols, edge_vals, grelC, binnedC, NE, NCOARSE, ngemm);
    passA2_kernel<<<NCOARSE * 16, 256, 0, stream>>>(binnedC, grelC, grelF, binnedF, NBUCK);
    spmm_sorted_kernel<<<NBUCK, 256, 0, stream>>>(Sup, binnedF, grelF, a_bias, out, NA);
}